// Round 20
// baseline (627.064 us; speedup 1.0000x reference)
//
#include <hip/hip_runtime.h>
#include <math.h>

#define B 4
#define N 8192
#define K 1024
#define BN (B * N)
#define RCH 8             // rows per chunk/block in sweepA
#define CPB (K / RCH)     // 128 chunks per batch
#define NCHK (B * CPB)    // 512 chunks total = sweepA grid
#define TPA 1024          // sweepA threads; 8 floats per thread per row

// Online lse in float: exp args are always <= 0 (no overflow); __expf(-inf)=0.
__device__ __forceinline__ void lse_step(float v, float& m, float& s) {
  float nm = fmaxf(m, v);
  s = s * __expf(m - nm) + __expf(v - nm);
  m = nm;
}
__device__ __forceinline__ void lse_merge(float m2, float s2, float& m, float& s) {
  float nm = fmaxf(m, m2);
  s = s * __expf(m - nm) + s2 * __expf(m2 - nm);
  m = nm;
}

// One g-sweep per Sinkhorn iteration. Block owns RCH=8 full rows of batch b.
// R17 lesson: 2 sub-chunks x 2 barriers drained the memory pipe (3.6 TB/s).
// Now: load ALL 8 rows into regs up front (16 back-to-back float4 loads),
// A1 all rows with only wave-level shfl (no block barrier), ONE sync, compute
// all rns, ONE sync, A2 all rows from the held registers (single g read).
template <bool SUB>
__device__ __forceinline__ void sweepA_body(const float* __restrict__ g,
                                            const float* __restrict__ d,
                                            float* __restrict__ part) {
  __shared__ float2 wpart[RCH][16];  // [row][wave]
  __shared__ float rns[RCH];         // r for the 8 rows
  const int blk = blockIdx.x;
  const int b = blk >> 7;  // CPB == 128
  const int k0 = (blk & (CPB - 1)) * RCH;
  const int t = threadIdx.x, lane = t & 63, wv = t >> 6;
  const float* gbase = g + ((size_t)(b * K + k0)) * N;

  float4 dv[2];
  if (SUB) {
#pragma unroll
    for (int j = 0; j < 2; ++j)
      dv[j] = *(const float4*)(d + (size_t)b * N + j * 4096 + t * 4);
  }

  // Load all 8 rows (64 VGPRs payload) — maximal MLP, no barrier in between.
  float4 gv[RCH][2];
#pragma unroll
  for (int r = 0; r < RCH; ++r)
#pragma unroll
    for (int j = 0; j < 2; ++j)
      gv[r][j] = *(const float4*)(gbase + (size_t)r * N + j * 4096 + t * 4);

  if (SUB) {
    // A1: per-row lse of g + d (2-way ILP), wave shfl reduce, LDS stash. No
    // block barrier inside this loop — rows stream while reduces compute.
#pragma unroll
    for (int r = 0; r < RCH; ++r) {
      float m0 = -INFINITY, s0 = 0.f, m1 = -INFINITY, s1 = 0.f;
      lse_step(gv[r][0].x + dv[0].x, m0, s0);
      lse_step(gv[r][0].y + dv[0].y, m1, s1);
      lse_step(gv[r][0].z + dv[0].z, m0, s0);
      lse_step(gv[r][0].w + dv[0].w, m1, s1);
      lse_step(gv[r][1].x + dv[1].x, m0, s0);
      lse_step(gv[r][1].y + dv[1].y, m1, s1);
      lse_step(gv[r][1].z + dv[1].z, m0, s0);
      lse_step(gv[r][1].w + dv[1].w, m1, s1);
      lse_merge(m1, s1, m0, s0);
#pragma unroll
      for (int off = 32; off; off >>= 1) {
        float mm = __shfl_down(m0, off, 64);
        float ss = __shfl_down(s0, off, 64);
        lse_merge(mm, ss, m0, s0);
      }
      if (lane == 0) wpart[r][wv] = make_float2(m0, s0);
    }
    __syncthreads();
    if (t < 16 * RCH) {  // t = row*16 + wentry; 2 waves cover all 8 rows
      float2 e = wpart[t >> 4][t & 15];
      float m = e.x, s = e.y;
#pragma unroll
      for (int off = 1; off < 16; off <<= 1) {
        float mm = __shfl_xor(m, off, 64);
        float ss = __shfl_xor(s, off, 64);
        lse_merge(mm, ss, m, s);
      }
      if ((t & 15) == 0) rns[t >> 4] = m + __logf(s);
    }
    __syncthreads();
  }

  // A2: col-partial accumulate from the SAME registers (no second g read)
  float cm[2][4], cs[2][4];
#pragma unroll
  for (int j = 0; j < 2; ++j)
#pragma unroll
    for (int q = 0; q < 4; ++q) { cm[j][q] = -INFINITY; cs[j][q] = 0.f; }
#pragma unroll
  for (int r = 0; r < RCH; ++r) {
    float rk = SUB ? rns[r] : 0.f;
#pragma unroll
    for (int j = 0; j < 2; ++j) {
      lse_step(gv[r][j].x - rk, cm[j][0], cs[j][0]);
      lse_step(gv[r][j].y - rk, cm[j][1], cs[j][1]);
      lse_step(gv[r][j].z - rk, cm[j][2], cs[j][2]);
      lse_step(gv[r][j].w - rk, cm[j][3], cs[j][3]);
    }
  }
  float* pp = part + (size_t)blk * N;
#pragma unroll
  for (int j = 0; j < 2; ++j) {
    float4 o = make_float4(cm[j][0] + __logf(cs[j][0]), cm[j][1] + __logf(cs[j][1]),
                           cm[j][2] + __logf(cs[j][2]), cm[j][3] + __logf(cs[j][3]));
    *(float4*)(pp + j * 4096 + t * 4) = o;
  }
}

__global__ __launch_bounds__(TPA) void sweepA0_kernel(const float* __restrict__ g,
                                                      const float* __restrict__ d,
                                                      float* __restrict__ part) {
  sweepA_body<false>(g, d, part);
}
__global__ __launch_bounds__(TPA) void sweepA1_kernel(const float* __restrict__ g,
                                                      const float* __restrict__ d,
                                                      float* __restrict__ part) {
  sweepA_body<true>(g, d, part);
}

// Fold CPB=128 chunk-partials per column -> d[b*N+n] = -lse_k(...).
// 8 p-groups x 16 chunks each + LDS merge (R2-proven shape).
__global__ __launch_bounds__(256) void sweepB_kernel(const float* __restrict__ part,
                                                     float* __restrict__ d) {
  int c = threadIdx.x & 31;   // column within block
  int pg = threadIdx.x >> 5;  // p-group 0..7
  int idx = blockIdx.x * 32 + c;  // b*N + n
  int b = idx >> 13;              // N == 8192
  int n = idx & (N - 1);
  const float* pp = part + ((size_t)(b * CPB + pg * 16)) * N + n;
  float m = -INFINITY, s = 0.f;
#pragma unroll
  for (int i = 0; i < 16; ++i) lse_step(pp[(size_t)i * N], m, s);
  __shared__ float2 red[8][32];
  red[pg][c] = make_float2(m, s);
  __syncthreads();
  if (threadIdx.x < 32) {
    float mm = red[0][threadIdx.x].x, ss = red[0][threadIdx.x].y;
#pragma unroll
    for (int w = 1; w < 8; ++w)
      lse_merge(red[w][threadIdx.x].x, red[w][threadIdx.x].y, mm, ss);
    d[blockIdx.x * 32 + threadIdx.x] = -(mm + __logf(ss));
  }
}

// out[row] = 1.0; out[B*K+row] = argmax_n(g[row,:] + d[b,:]) (first-index ties)
__global__ __launch_bounds__(256) void argmax_kernel(const float* __restrict__ g,
                                                     const float* __restrict__ d,
                                                     float* __restrict__ out) {
  int row = blockIdx.x;  // b*K + k
  int b = row >> 10;
  const float* gp = g + (size_t)row * N;
  const float* dp = d + b * N;
  float bv = -INFINITY;
  int bi = 0;
#pragma unroll
  for (int j = 0; j < 8; ++j) {
    int n = j * 1024 + threadIdx.x * 4;
    float4 gv = *(const float4*)(gp + n);
    float4 dv = *(const float4*)(dp + n);
    float v;
    v = gv.x + dv.x; if (v > bv) { bv = v; bi = n + 0; }
    v = gv.y + dv.y; if (v > bv) { bv = v; bi = n + 1; }
    v = gv.z + dv.z; if (v > bv) { bv = v; bi = n + 2; }
    v = gv.w + dv.w; if (v > bv) { bv = v; bi = n + 3; }
  }
  __shared__ float svv[256];
  __shared__ int sii[256];
  svv[threadIdx.x] = bv;
  sii[threadIdx.x] = bi;
  __syncthreads();
  for (int off = 128; off > 0; off >>= 1) {
    if (threadIdx.x < off) {
      float v2 = svv[threadIdx.x + off];
      int i2 = sii[threadIdx.x + off];
      float v1 = svv[threadIdx.x];
      int i1 = sii[threadIdx.x];
      if (v2 > v1 || (v2 == v1 && i2 < i1)) {
        svv[threadIdx.x] = v2;
        sii[threadIdx.x] = i2;
      }
    }
    __syncthreads();
  }
  if (threadIdx.x == 0) {
    out[row] = 1.0f;                   // selected_scores forward value (all-true mask)
    out[B * K + row] = (float)sii[0];  // selected_indices as float
  }
}

extern "C" void kernel_launch(void* const* d_in, const int* in_sizes, int n_in,
                              void* d_out, int out_size, void* d_ws, size_t ws_size,
                              hipStream_t stream) {
  // x, routing_token cancel out of the forward outputs (scores constant along k,
  // removed exactly by the first column logsumexp). Only gumbel matters.
  const float* g = (const float*)d_in[2];
  float* out = (float*)d_out;

  char* ws = (char*)d_ws;
  float* d = (float*)ws;                    // 128 KB: d[b*N+n] = -lse_k(...)
  float* part = (float*)(ws + (1 << 20));   // 16 MB: NCHK x N chunk col-partials

  // iter 1 col-update: d1 = -lse_k(g)
  sweepA0_kernel<<<NCHK, TPA, 0, stream>>>(g, d, part);
  sweepB_kernel<<<BN / 32, 256, 0, stream>>>(part, d);
  // iters 2..8: r_i = lse_n(g + d_i) block-local; d_{i+1} = -lse_k(g - r_i)
  for (int it = 0; it < 7; ++it) {
    sweepA1_kernel<<<NCHK, TPA, 0, stream>>>(g, d, part);
    sweepB_kernel<<<BN / 32, 256, 0, stream>>>(part, d);
  }
  // 8th row update shifts each row uniformly -> argmax unaffected; skip it.
  argmax_kernel<<<B * K, 256, 0, stream>>>(g, d, out);
}